// Round 1
// 1677.008 us; speedup vs baseline: 1.0246x; 1.0246x over previous
//
#include <hip/hip_runtime.h>
#include <stdint.h>

typedef __bf16 bf16;
typedef __bf16 bf16x8 __attribute__((ext_vector_type(8)));
typedef float  f32x4  __attribute__((ext_vector_type(4)));

// recurrence decomposition: per (dir,stage) NB blocks of 512 threads, 16 units each
#define NB 16
// ws layout (bytes)
#define OFF_CTR    0
#define CTR_BYTES  (4*128*4)
#define OFF_HIST   2048
#define HIST_ONE   (128*32*256*2)            // 2 MB per hist (128 slots of [32][256] bf16)
#define OFF_H0F    (OFF_HIST)
#define OFF_H0B    (OFF_HIST + 1*HIST_ONE)
#define OFF_H1F    (OFF_HIST + 2*HIST_ONE)
#define OFF_H1B    (OFF_HIST + 3*HIST_ONE)
#define OFF_XF     (OFF_HIST + 4*HIST_ONE)   // 8,390,656
#define XF_BYTES   (4064*256*2)
#define OFF_XB     (OFF_XF + XF_BYTES)
#define OFF_FW0T   (OFF_XB + XF_BYTES)
#define W0T_BYTES  (1024*256*2)
#define OFF_BW0T   (OFF_FW0T + W0T_BYTES)
#define OFF_PRE0F  (OFF_BW0T + W0T_BYTES)
#define PRE_BYTES  (4064*1024*4)
#define OFF_PRE0B  (OFF_PRE0F + PRE_BYTES)
#define OFF_WPT    (OFF_PRE0B + PRE_BYTES)
#define WPT_BYTES  (32000*512*2)
#define OFF_CTX    (OFF_WPT + WPT_BYTES)
#define CTX_BYTES  (4032*512*2)
#define OFF_MF     (OFF_CTX + CTX_BYTES)
#define OFF_MB     (OFF_MF + 4096)

__device__ __forceinline__ int swz8(int row, int kblk) { return (kblk ^ (row & 7)) << 3; }

// system-scope (MALL-coherent, cache-bypassing) helpers — no L2 flush/inv needed
__device__ __forceinline__ uint64_t sys_load_u64(const uint64_t* p) {
  return __hip_atomic_load(p, __ATOMIC_RELAXED, __HIP_MEMORY_SCOPE_SYSTEM);
}
__device__ __forceinline__ void sys_store_u16(unsigned short* p, unsigned short v) {
  __hip_atomic_store(p, v, __ATOMIC_RELAXED, __HIP_MEMORY_SCOPE_SYSTEM);
}
__device__ __forceinline__ int sys_load_i32(const int* p) {
  return __hip_atomic_load(p, __ATOMIC_RELAXED, __HIP_MEMORY_SCOPE_SYSTEM);
}
__device__ __forceinline__ void sys_store_i32(int* p, int v) {
  __hip_atomic_store(p, v, __ATOMIC_RELAXED, __HIP_MEMORY_SCOPE_SYSTEM);
}

// parallel per-block flag wait: 16 lanes each watch one producer flag, then barrier.
__device__ __forceinline__ void wait_flags(const int* f, int want, int tid) {
  if (tid < NB) {
    int spins = 0;
    while (sys_load_i32(&f[tid]) < want) {
      if (++spins > (1<<16)) __builtin_amdgcn_s_sleep(2);
      if (spins > (1<<20)) break;   // hang safety
    }
  }
  __atomic_signal_fence(__ATOMIC_SEQ_CST);
  __syncthreads();
}

// global->LDS direct staging (16B/lane; LDS dest = wave-uniform base + lane*16)
typedef __attribute__((address_space(1))) unsigned int as1_u32;
typedef __attribute__((address_space(3))) unsigned int as3_u32;
__device__ __forceinline__ void gload16(const void* g, void* l) {
  __builtin_amdgcn_global_load_lds((as1_u32*)g, (as3_u32*)l, 16, 0, 0);
}

// ---------------- embedding gather + masks (builds xf/xb bf16, t-major) ----------------
__global__ __launch_bounds__(256) void embed_kernel(
    const int* __restrict__ x, const float* __restrict__ tab,
    bf16* __restrict__ xf, bf16* __restrict__ xb,
    unsigned char* __restrict__ mf, unsigned char* __restrict__ mb)
{
  int t = blockIdx.x;      // 0..126
  int b = blockIdx.y;      // 0..31
  int k = threadIdx.x;     // 0..255
  int tokf = x[b*128 + t];          // fwd consumes token t
  int tokb = x[b*128 + 127 - t];    // bwd step s=t consumes token 127-t
  xf[(size_t)(t*32+b)*256 + k] = (bf16)tab[(size_t)tokf*256 + k];
  xb[(size_t)(t*32+b)*256 + k] = (bf16)tab[(size_t)tokb*256 + k];
  if (k == 0) { mf[t*32+b] = (tokf != 0); mb[t*32+b] = (tokb != 0); }
}

// ---------------- f32 [R][C] -> bf16 [C][R] transpose ----------------
__global__ __launch_bounds__(256) void transpose_to_bf16(
    const float* __restrict__ in, bf16* __restrict__ out, int R, int C)
{
  __shared__ float tile[64][65];
  int c0 = blockIdx.x*64, r0 = blockIdx.y*64;
  int tid = threadIdx.x;
  int r = tid >> 2, cs = (tid & 3)*16;
  #pragma unroll
  for (int i = 0; i < 16; i += 4) {
    float4 v = *(const float4*)(in + (size_t)(r0+r)*C + c0 + cs + i);
    tile[r][cs+i+0]=v.x; tile[r][cs+i+1]=v.y; tile[r][cs+i+2]=v.z; tile[r][cs+i+3]=v.w;
  }
  __syncthreads();
  int c = tid >> 2, rs = (tid & 3)*16;
  #pragma unroll
  for (int i = 0; i < 16; ++i)
    out[(size_t)(c0+c)*R + r0 + rs + i] = (bf16)tile[rs+i][c];
}

// ---------------- bf16 MFMA GEMM: C[M][N] = A[M][K] * BT[N][K]^T + bias[N] ----------------
// m97-style staging: global_load_lds width-16 into linear [128][64] LDS tiles.
__global__ __launch_bounds__(256) void gemm_bf16(
    const bf16* __restrict__ A, const bf16* __restrict__ BT,
    const float* __restrict__ bias, float* __restrict__ C,
    int M, int N, int K)
{
  __shared__ bf16 As[128][64];
  __shared__ bf16 Bs[128][64];
  int tid = threadIdx.x;
  int row0 = blockIdx.x*128, col0 = blockIdx.y*128;
  int wave = tid >> 6, lane = tid & 63, l15 = lane & 15, quad = lane >> 4;
  int wm = (wave & 1)*64, wn = (wave >> 1)*64;
  int lr = lane >> 3;            // row within 8-row group (0..7)
  int lc = (lane & 7)*8;         // element col offset (0..56)
  f32x4 acc[4][4] = {};
  for (int kk = 0; kk < K; kk += 64) {
    #pragma unroll
    for (int i = 0; i < 4; ++i) {
      int rb = (wave*4 + i)*8;                      // 8-row group base
      int ga = row0 + rb + lr; if (ga > M-1) ga = M-1;   // per-lane clamp (OOB rows discarded at C-write)
      gload16(A  + (size_t)ga*K + kk + lc,                 &As[rb][0]);
      gload16(BT + (size_t)(col0 + rb + lr)*K + kk + lc,   &Bs[rb][0]);
    }
    __syncthreads();   // implicit vmcnt(0) drain of global_load_lds
    #pragma unroll
    for (int ks = 0; ks < 64; ks += 32) {
      bf16x8 af[4], bfr[4];
      #pragma unroll
      for (int mi = 0; mi < 4; ++mi) af[mi]  = *(const bf16x8*)&As[wm + mi*16 + l15][ks + quad*8];
      #pragma unroll
      for (int ni = 0; ni < 4; ++ni) bfr[ni] = *(const bf16x8*)&Bs[wn + ni*16 + l15][ks + quad*8];
      #pragma unroll
      for (int mi = 0; mi < 4; ++mi)
        #pragma unroll
        for (int ni = 0; ni < 4; ++ni)
          acc[mi][ni] = __builtin_amdgcn_mfma_f32_16x16x32_bf16(af[mi], bfr[ni], acc[mi][ni], 0, 0, 0);
    }
    __syncthreads();
  }
  #pragma unroll
  for (int ni = 0; ni < 4; ++ni) {
    int col = col0 + wn + ni*16 + l15;
    float bv = bias[col];
    #pragma unroll
    for (int mi = 0; mi < 4; ++mi) {
      int rbase = row0 + wm + mi*16 + quad*4;
      #pragma unroll
      for (int r = 0; r < 4; ++r) {
        int grow = rbase + r;
        if (grow < M) C[(size_t)grow*N + col] = acc[mi][ni][r] + bv;
      }
    }
  }
}

// ---------------- persistent pipelined LSTM recurrence (MALL-coherent handoff) ----------------
// grid = 64 blocks x 512 threads: dir(2) x stage(2) x NB(16). Each block owns 16 units (64 z-cols).
// Sync via per-block flag words (monotone step counts) at system scope: producer posts t+1 after
// draining its h stores; consumers poll the 16 flags with 16 parallel lanes (no RMW serialization).
// Stage 1 is phase-split: PhaseA = wait stage0 (runs ahead -> free) + W1*h0(t) MFMA; PhaseB = wait
// own peers (discovery hidden under PhaseA) + U1*h1(t-1) MFMA. The c1 chain segment is halved.
__global__ __launch_bounds__(512) void recur_kernel(
    const float* __restrict__ pre0f, const float* __restrict__ pre0b,
    const float* __restrict__ fU0, const float* __restrict__ bU0,
    const float* __restrict__ fW1, const float* __restrict__ fU1,
    const float* __restrict__ bW1, const float* __restrict__ bU1,
    const float* __restrict__ fb1, const float* __restrict__ bb1,
    const unsigned char* __restrict__ mf, const unsigned char* __restrict__ mb,
    bf16* __restrict__ h0f, bf16* __restrict__ h0b,
    bf16* __restrict__ h1f, bf16* __restrict__ h1b,
    int* __restrict__ ctr)
{
  __shared__ bf16 U_T[64][512];   // [lds-col][k], octs swizzled by (col&7)  (64KB)
  __shared__ bf16 hA[32][512];    // [b][k], octs swizzled by (b&7)          (32KB)
  __shared__ float z_s[32][65];   // separate z buffer (8.3KB) — no hA aliasing

  int tid = threadIdx.x;
  int bx = blockIdx.x;
  int dir = bx >> 5, stage = (bx >> 4) & 1, blk = bx & 15;
  int j0 = blk * 16;
  const float* pre = dir ? pre0b : pre0f;
  const unsigned char* mgl = dir ? mb : mf;
  bf16* h0 = dir ? h0b : h0f;
  bf16* h1 = dir ? h1b : h1f;
  int* f0 = ctr + (dir*2 + 0)*16;   // stage-0 per-block flags
  int* f1 = ctr + (dir*2 + 1)*16;   // stage-1 per-block flags

  // ---- one-time: weight slice -> LDS (bf16, [col][k], k-major loop for coalescing) ----
  if (stage == 0) {
    const float* U = dir ? bU0 : fU0;
    for (int idx = tid; idx < 64*256; idx += 512) {
      int k = idx >> 6, c = idx & 63;
      int gc = (c >> 4)*256 + j0 + (c & 15);
      U_T[c][swz8(c, k >> 3) | (k & 7)] = (bf16)U[(size_t)k*1024 + gc];
    }
  } else {
    const float* W = dir ? bW1 : fW1;
    const float* U = dir ? bU1 : fU1;
    for (int idx = tid; idx < 64*512; idx += 512) {
      int k = idx >> 6, c = idx & 63;
      int gc = (c >> 4)*256 + j0 + (c & 15);
      float v = (k < 256) ? W[(size_t)k*1024 + gc] : U[(size_t)(k-256)*1024 + gc];
      U_T[c][swz8(c, k >> 3) | (k & 7)] = (bf16)v;
    }
  }
  int gb = tid & 31, gu = tid >> 5;        // gate thread: batch gb, unit j0+gu  (gu 0..15)
  float c_state = 0.f, h_state = 0.f;
  float bi = 0.f, bff = 0.f, bgg = 0.f, boo = 0.f;
  if (stage == 1) {
    const float* bias = dir ? bb1 : fb1;
    bi  = bias[0*256 + j0 + gu];
    bff = bias[1*256 + j0 + gu];
    bgg = bias[2*256 + j0 + gu];
    boo = bias[3*256 + j0 + gu];
  }
  int wave = tid >> 6, lane = tid & 63, l15 = lane & 15, quad = lane >> 4;
  int m0 = (wave & 1)*16, n0 = (wave >> 1)*16;     // 2 m-tiles x 4 n-tiles = 8 waves
  __syncthreads();

  for (int t = 0; t < 127; ++t) {
    // step-constant operands (independent of handoff — issue early)
    float p_i = bi, p_f = bff, p_g = bgg, p_o = boo;
    if (stage == 0) {
      const float* p = pre + ((size_t)t*32 + gb)*1024 + j0 + gu;
      p_i = p[0]; p_f = p[256]; p_g = p[512]; p_o = p[768];
    }
    unsigned char msk = mgl[t*32 + gb];
    f32x4 acc = {0.f, 0.f, 0.f, 0.f};

    if (stage == 0) {
      // wait peers completed step t-1 (h0(t-1) at slot t posted with flag >= t)
      if (t > 0) wait_flags(f0, t, tid);
      const uint64_t* src = (const uint64_t*)(h0 + (size_t)t*8192);
      #pragma unroll
      for (int i = 0; i < 4; ++i) {
        int q = i*512 + tid;                 // 2048 qwords (16KB)
        int r = q >> 6, seg = q & 63;
        uint64_t v = sys_load_u64(src + q);
        *(uint64_t*)&hA[r][swz8(r, seg >> 1) + (seg & 1)*4] = v;
      }
      __syncthreads();
      for (int kc = 0; kc < 256; kc += 32) {
        int kb = (kc >> 3) + quad;
        bf16x8 a = *(const bf16x8*)&hA[m0 + l15][swz8(m0 + l15, kb)];
        bf16x8 w = *(const bf16x8*)&U_T[n0 + l15][swz8(n0 + l15, kb)];
        acc = __builtin_amdgcn_mfma_f32_16x16x32_bf16(a, w, acc, 0, 0, 0);
      }
    } else {
      // ---- Phase A: W1 * h0(t)  (stage0 runs ahead; this wait is normally satisfied) ----
      wait_flags(f0, t+1, tid);
      const uint64_t* s0p = (const uint64_t*)(h0 + (size_t)(t+1)*8192);  // h0(t)
      #pragma unroll
      for (int i = 0; i < 4; ++i) {
        int q = i*512 + tid;
        int r = q >> 6, seg = q & 63;
        uint64_t v = sys_load_u64(s0p + q);
        *(uint64_t*)&hA[r][swz8(r, seg >> 1) + (seg & 1)*4] = v;   // octs 0..31
      }
      __syncthreads();
      for (int kc = 0; kc < 256; kc += 32) {
        int kb = (kc >> 3) + quad;
        bf16x8 a = *(const bf16x8*)&hA[m0 + l15][swz8(m0 + l15, kb)];
        bf16x8 w = *(const bf16x8*)&U_T[n0 + l15][swz8(n0 + l15, kb)];
        acc = __builtin_amdgcn_mfma_f32_16x16x32_bf16(a, w, acc, 0, 0, 0);
      }
      // ---- Phase B: U1 * h1(t-1)  (peer-flag discovery overlapped by Phase A) ----
      if (t > 0) wait_flags(f1, t, tid);
      const uint64_t* s1p = (const uint64_t*)(h1 + (size_t)t*8192);      // h1(t-1)
      #pragma unroll
      for (int i = 0; i < 4; ++i) {
        int q = i*512 + tid;
        int r = q >> 6, seg = q & 63;
        uint64_t v = sys_load_u64(s1p + q);
        *(uint64_t*)&hA[r][swz8(r, (seg >> 1) + 32) + (seg & 1)*4] = v; // octs 32..63 (disjoint)
      }
      __syncthreads();
      for (int kc = 256; kc < 512; kc += 32) {
        int kb = (kc >> 3) + quad;
        bf16x8 a = *(const bf16x8*)&hA[m0 + l15][swz8(m0 + l15, kb)];
        bf16x8 w = *(const bf16x8*)&U_T[n0 + l15][swz8(n0 + l15, kb)];
        acc = __builtin_amdgcn_mfma_f32_16x16x32_bf16(a, w, acc, 0, 0, 0);
      }
    }

    // z to LDS (separate buffer — no alias barrier needed before the write)
    #pragma unroll
    for (int r = 0; r < 4; ++r) z_s[m0 + quad*4 + r][n0 + l15] = acc[r];
    __syncthreads();   // [C2]

    // gates (fp32, Keras order i,f,g,o); lds col for (gate g, unit gu) = g*16+gu
    float zi = z_s[gb][ 0 + gu] + p_i;
    float zf = z_s[gb][16 + gu] + p_f;
    float zg = z_s[gb][32 + gu] + p_g;
    float zo = z_s[gb][48 + gu] + p_o;
    float ig = 1.f/(1.f + expf(-zi));
    float fg = 1.f/(1.f + expf(-zf));
    float gg = tanhf(zg);
    float og = 1.f/(1.f + expf(-zo));
    float cn = fg*c_state + ig*gg;
    float hn = og*tanhf(cn);
    if (msk) { c_state = cn; h_state = hn; }

    // store h to MALL (system scope), drain own store, barrier, then post own flag (parallel stores)
    bf16 hv = (bf16)h_state;
    unsigned short hb;
    __builtin_memcpy(&hb, &hv, 2);
    unsigned short* dst = (unsigned short*)((stage == 0 ? h0 : h1) + (size_t)(t+1)*8192 + gb*256 + j0 + gu);
    sys_store_u16(dst, hb);
    asm volatile("s_waitcnt vmcnt(0)" ::: "memory");
    __syncthreads();   // [D] every thread's store is at the MALL
    if (tid == 0) {
      __atomic_signal_fence(__ATOMIC_SEQ_CST);
      sys_store_i32(stage == 0 ? &f0[blk] : &f1[blk], t+1);
    }
    // no trailing barrier: next iteration's wait_flags barrier (incl. own flag) covers ordering
  }
}

// ---------------- ctx assembly: ctx[b*126+tau][0:256]=h1f(tau), [256:512]=h1b(tau+1) ----------------
__global__ __launch_bounds__(256) void ctx_kernel(
    const bf16* __restrict__ h1f, const bf16* __restrict__ h1b, bf16* __restrict__ ctx)
{
  int tau = blockIdx.x;   // 0..125
  int b = blockIdx.y;     // 0..31
  int k = threadIdx.x;    // 0..255
  size_t r = (size_t)(b*126 + tau)*512;
  ctx[r + k]       = h1f[(size_t)(tau+1)*8192 + b*256 + k];   // f[b][tau]  -> slot tau+1
  ctx[r + 256 + k] = h1b[(size_t)(tau+2)*8192 + b*256 + k];   // b_out[b][tau+1] -> slot tau+2
}

// ---------------- NSP head ----------------
__global__ __launch_bounds__(256) void nsp_kernel(
    const bf16* __restrict__ ctx, const float* __restrict__ Wn,
    const float* __restrict__ bn, float* __restrict__ out)
{
  int b = blockIdx.x, tid = threadIdx.x;
  const unsigned short* cb = (const unsigned short*)ctx;
  float a0 = 0.f, a1 = 0.f;
  for (int flat = tid; flat < 64512; flat += 256) {
    int tau = flat >> 9, k = flat & 511;
    float cv = __uint_as_float((unsigned)cb[(size_t)(b*126 + tau)*512 + k] << 16);
    float2 w = *(const float2*)(Wn + 2*(size_t)flat);
    a0 += cv*w.x; a1 += cv*w.y;
  }
  __shared__ float r0[256], r1[256];
  r0[tid] = a0; r1[tid] = a1;
  __syncthreads();
  for (int s = 128; s > 0; s >>= 1) {
    if (tid < s) { r0[tid] += r0[tid+s]; r1[tid] += r1[tid+s]; }
    __syncthreads();
  }
  if (tid == 0) { out[b*2+0] = r0[0] + bn[0]; out[b*2+1] = r1[0] + bn[1]; }
}

// ---------------- launch ----------------
extern "C" void kernel_launch(void* const* d_in, const int* in_sizes, int n_in,
                              void* d_out, int out_size, void* d_ws, size_t ws_size,
                              hipStream_t stream)
{
  const int*   x   = (const int*)d_in[0];
  const float* tab = (const float*)d_in[1];
  const float* fW  = (const float*)d_in[2];
  const float* fU  = (const float*)d_in[3];
  const float* fb  = (const float*)d_in[4];
  const float* bW  = (const float*)d_in[5];
  const float* bU  = (const float*)d_in[6];
  const float* bb  = (const float*)d_in[7];
  const float* Wp  = (const float*)d_in[8];
  const float* bp  = (const float*)d_in[9];
  const float* Wn  = (const float*)d_in[10];
  const float* bn  = (const float*)d_in[11];
  float* out = (float*)d_out;
  char* ws = (char*)d_ws;

  int*  ctr   = (int*)(ws + OFF_CTR);
  bf16* h0f   = (bf16*)(ws + OFF_H0F);
  bf16* h0b   = (bf16*)(ws + OFF_H0B);
  bf16* h1f   = (bf16*)(ws + OFF_H1F);
  bf16* h1b   = (bf16*)(ws + OFF_H1B);
  bf16* xf    = (bf16*)(ws + OFF_XF);
  bf16* xb    = (bf16*)(ws + OFF_XB);
  bf16* fW0T  = (bf16*)(ws + OFF_FW0T);
  bf16* bW0T  = (bf16*)(ws + OFF_BW0T);
  float* pre0f = (float*)(ws + OFF_PRE0F);
  float* pre0b = (float*)(ws + OFF_PRE0B);
  bf16* WpT   = (bf16*)(ws + OFF_WPT);
  bf16* ctx   = (bf16*)(ws + OFF_CTX);
  unsigned char* mf = (unsigned char*)(ws + OFF_MF);
  unsigned char* mb = (unsigned char*)(ws + OFF_MB);

  // only flags + the t=0 h slots are read-before-write; skip the 8.4MB blanket memset
  hipMemsetAsync(ws + OFF_CTR, 0, CTR_BYTES, stream);
  hipMemsetAsync(ws + OFF_H0F, 0, 16384, stream);
  hipMemsetAsync(ws + OFF_H0B, 0, 16384, stream);
  hipMemsetAsync(ws + OFF_H1F, 0, 16384, stream);
  hipMemsetAsync(ws + OFF_H1B, 0, 16384, stream);

  embed_kernel<<<dim3(127, 32), 256, 0, stream>>>(x, tab, xf, xb, mf, mb);

  transpose_to_bf16<<<dim3(16, 4),  256, 0, stream>>>(fW, fW0T, 256, 1024);
  transpose_to_bf16<<<dim3(16, 4),  256, 0, stream>>>(bW, bW0T, 256, 1024);
  transpose_to_bf16<<<dim3(500, 8), 256, 0, stream>>>(Wp, WpT, 512, 32000);

  gemm_bf16<<<dim3(32, 8), 256, 0, stream>>>(xf, fW0T, fb, pre0f, 4064, 1024, 256);
  gemm_bf16<<<dim3(32, 8), 256, 0, stream>>>(xb, bW0T, bb, pre0b, 4064, 1024, 256);

  recur_kernel<<<64, 512, 0, stream>>>(
      pre0f, pre0b,
      fU, bU,
      fW + 262144, fU + 262144, bW + 262144, bU + 262144,
      fb + 1024, bb + 1024,
      mf, mb, h0f, h0b, h1f, h1b, ctr);

  ctx_kernel<<<dim3(126, 32), 256, 0, stream>>>(h1f, h1b, ctx);

  gemm_bf16<<<dim3(32, 250), 256, 0, stream>>>(ctx, WpT, bp, out, 4032, 32000, 512);

  nsp_kernel<<<32, 256, 0, stream>>>(ctx, Wn, bn, out + (size_t)4032*32000);
}

// Round 2
// 1486.548 us; speedup vs baseline: 1.1559x; 1.1281x over previous
//
#include <hip/hip_runtime.h>
#include <stdint.h>

typedef __bf16 bf16;
typedef __bf16 bf16x8 __attribute__((ext_vector_type(8)));
typedef float  f32x4  __attribute__((ext_vector_type(4)));

#define NB 16
// ---------------- ws layout (bytes) ----------------
// tagged h arrays: u32 {tag(hi16), h bf16(lo16)}, 128 slots x [blk16][b32][u16] = 32KB/slot
#define OFF_MF     0
#define OFF_MB     4096
#define OFF_H0F    8192
#define TAG_ONE    (128*32*256*4)                 // 4,194,304
#define OFF_H0B    (OFF_H0F + 1*TAG_ONE)
#define OFF_H1F    (OFF_H0F + 2*TAG_ONE)
#define OFF_H1B    (OFF_H0F + 3*TAG_ONE)
#define OFF_XF     (OFF_H0F + 4*TAG_ONE)          // 16,785,408
#define XF_BYTES   (4064*256*2)
#define OFF_XB     (OFF_XF + XF_BYTES)
#define OFF_FW0T   (OFF_XB + XF_BYTES)            // 20,946,944
#define W0T_BYTES  (1024*256*2)
#define OFF_BW0T   (OFF_FW0T + W0T_BYTES)
#define OFF_PRE0F  (OFF_BW0T + W0T_BYTES)         // 21,995,520
#define PRE_BYTES  (4064*1024*4)
#define OFF_PRE0B  (OFF_PRE0F + PRE_BYTES)        // end 55,287,808
// aliases (used only after recur; sources dead by then):
#define OFF_WPT    OFF_PRE0F                      // 32,768,000 <= 2*PRE ✓
#define OFF_CTX    OFF_XF                         // 4,128,768 <= XF+XB ✓

__device__ __forceinline__ int swz8(int row, int kblk) { return (kblk ^ (row & 7)) << 3; }

// system-scope (MALL-coherent, cache-bypassing) helpers
__device__ __forceinline__ uint64_t sys_load_u64(const uint64_t* p) {
  return __hip_atomic_load(p, __ATOMIC_RELAXED, __HIP_MEMORY_SCOPE_SYSTEM);
}
__device__ __forceinline__ void sys_store_u32(uint32_t* p, uint32_t v) {
  __hip_atomic_store(p, v, __ATOMIC_RELAXED, __HIP_MEMORY_SCOPE_SYSTEM);
}

// global->LDS direct staging (16B/lane)
typedef __attribute__((address_space(1))) unsigned int as1_u32;
typedef __attribute__((address_space(3))) unsigned int as3_u32;
__device__ __forceinline__ void gload16(const void* g, void* l) {
  __builtin_amdgcn_global_load_lds((as1_u32*)g, (as3_u32*)l, 16, 0, 0);
}

// ---------------- embedding gather + masks ----------------
__global__ __launch_bounds__(256) void embed_kernel(
    const int* __restrict__ x, const float* __restrict__ tab,
    bf16* __restrict__ xf, bf16* __restrict__ xb,
    unsigned char* __restrict__ mf, unsigned char* __restrict__ mb)
{
  int t = blockIdx.x;      // 0..126
  int b = blockIdx.y;      // 0..31
  int k = threadIdx.x;     // 0..255
  int tokf = x[b*128 + t];
  int tokb = x[b*128 + 127 - t];
  xf[(size_t)(t*32+b)*256 + k] = (bf16)tab[(size_t)tokf*256 + k];
  xb[(size_t)(t*32+b)*256 + k] = (bf16)tab[(size_t)tokb*256 + k];
  if (k == 0) { mf[t*32+b] = (tokf != 0); mb[t*32+b] = (tokb != 0); }
}

// ---------------- f32 [R][C] -> bf16 [C][R] transpose ----------------
__global__ __launch_bounds__(256) void transpose_to_bf16(
    const float* __restrict__ in, bf16* __restrict__ out, int R, int C)
{
  __shared__ float tile[64][65];
  int c0 = blockIdx.x*64, r0 = blockIdx.y*64;
  int tid = threadIdx.x;
  int r = tid >> 2, cs = (tid & 3)*16;
  #pragma unroll
  for (int i = 0; i < 16; i += 4) {
    float4 v = *(const float4*)(in + (size_t)(r0+r)*C + c0 + cs + i);
    tile[r][cs+i+0]=v.x; tile[r][cs+i+1]=v.y; tile[r][cs+i+2]=v.z; tile[r][cs+i+3]=v.w;
  }
  __syncthreads();
  int c = tid >> 2, rs = (tid & 3)*16;
  #pragma unroll
  for (int i = 0; i < 16; ++i)
    out[(size_t)(c0+c)*R + r0 + rs + i] = (bf16)tile[rs+i][c];
}

// ---------------- bf16 MFMA GEMM (m97-style global_load_lds staging) ----------------
__global__ __launch_bounds__(256) void gemm_bf16(
    const bf16* __restrict__ A, const bf16* __restrict__ BT,
    const float* __restrict__ bias, float* __restrict__ C,
    int M, int N, int K)
{
  __shared__ bf16 As[128][64];
  __shared__ bf16 Bs[128][64];
  int tid = threadIdx.x;
  int row0 = blockIdx.x*128, col0 = blockIdx.y*128;
  int wave = tid >> 6, lane = tid & 63, l15 = lane & 15, quad = lane >> 4;
  int wm = (wave & 1)*64, wn = (wave >> 1)*64;
  int lr = lane >> 3;
  int lc = (lane & 7)*8;
  f32x4 acc[4][4] = {};
  for (int kk = 0; kk < K; kk += 64) {
    #pragma unroll
    for (int i = 0; i < 4; ++i) {
      int rb = (wave*4 + i)*8;
      int ga = row0 + rb + lr; if (ga > M-1) ga = M-1;
      gload16(A  + (size_t)ga*K + kk + lc,                 &As[rb][0]);
      gload16(BT + (size_t)(col0 + rb + lr)*K + kk + lc,   &Bs[rb][0]);
    }
    __syncthreads();
    #pragma unroll
    for (int ks = 0; ks < 64; ks += 32) {
      bf16x8 af[4], bfr[4];
      #pragma unroll
      for (int mi = 0; mi < 4; ++mi) af[mi]  = *(const bf16x8*)&As[wm + mi*16 + l15][ks + quad*8];
      #pragma unroll
      for (int ni = 0; ni < 4; ++ni) bfr[ni] = *(const bf16x8*)&Bs[wn + ni*16 + l15][ks + quad*8];
      #pragma unroll
      for (int mi = 0; mi < 4; ++mi)
        #pragma unroll
        for (int ni = 0; ni < 4; ++ni)
          acc[mi][ni] = __builtin_amdgcn_mfma_f32_16x16x32_bf16(af[mi], bfr[ni], acc[mi][ni], 0, 0, 0);
    }
    __syncthreads();
  }
  #pragma unroll
  for (int ni = 0; ni < 4; ++ni) {
    int col = col0 + wn + ni*16 + l15;
    float bv = bias[col];
    #pragma unroll
    for (int mi = 0; mi < 4; ++mi) {
      int rbase = row0 + wm + mi*16 + quad*4;
      #pragma unroll
      for (int r = 0; r < 4; ++r) {
        int grow = rbase + r;
        if (grow < M) C[(size_t)grow*N + col] = acc[mi][ni][r] + bv;
      }
    }
  }
}

// ---------------- persistent LSTM recurrence — self-validating tagged handoff ----------------
// grid = 64 x 512: dir(2) x stage(2) x NB(16); block owns 16 units (64 z-cols).
// Each h element is a u32 {tag=slot (hi16), h bf16 (lo16)} stored with ONE relaxed system-scope
// store (fire-and-forget: no drain, no flag, no fence — the tag travels atomically with the data).
// Consumers batch-issue all granule loads (one MALL latency), tag-check, retry only stale ones.
// Slot s holds h(s-1), tag s (1..127); slot 0 never written (t=0 uses zeros); memset -> tag 0.
// h layout is block-major: u32 index = slot*8192 + blk*512 + b*16 + u  (== unit-major since each
// block owns contiguous units) -> producer stores are fully coalesced (index = blk*512 + tid).
__global__ __launch_bounds__(512) void recur_kernel(
    const float* __restrict__ pre0f, const float* __restrict__ pre0b,
    const float* __restrict__ fU0, const float* __restrict__ bU0,
    const float* __restrict__ fW1, const float* __restrict__ fU1,
    const float* __restrict__ bW1, const float* __restrict__ bU1,
    const float* __restrict__ fb1, const float* __restrict__ bb1,
    const unsigned char* __restrict__ mf, const unsigned char* __restrict__ mb,
    uint32_t* __restrict__ h0f, uint32_t* __restrict__ h0b,
    uint32_t* __restrict__ h1f, uint32_t* __restrict__ h1b)
{
  __shared__ bf16 U_T[64][512];   // [lds-col][k], octs swizzled by (col&7)  (64KB)
  __shared__ bf16 hA[32][512];    // [b][k], octs swizzled by (b&7)          (32KB)
  __shared__ float z_s[32][65];   // z buffer (8.3KB)

  int tid = threadIdx.x;
  int bx = blockIdx.x;
  int dir = bx >> 5, stage = (bx >> 4) & 1, blk = bx & 15;
  int j0 = blk * 16;
  const float* pre = dir ? pre0b : pre0f;
  const unsigned char* mgl = dir ? mb : mf;
  uint32_t* h0 = dir ? h0b : h0f;
  uint32_t* h1 = dir ? h1b : h1f;
  uint32_t* hout = stage ? h1 : h0;

  // ---- one-time: weight slice -> LDS ----
  if (stage == 0) {
    const float* U = dir ? bU0 : fU0;
    for (int idx = tid; idx < 64*256; idx += 512) {
      int k = idx >> 6, c = idx & 63;
      int gc = (c >> 4)*256 + j0 + (c & 15);
      U_T[c][swz8(c, k >> 3) | (k & 7)] = (bf16)U[(size_t)k*1024 + gc];
    }
  } else {
    const float* W = dir ? bW1 : fW1;
    const float* U = dir ? bU1 : fU1;
    for (int idx = tid; idx < 64*512; idx += 512) {
      int k = idx >> 6, c = idx & 63;
      int gc = (c >> 4)*256 + j0 + (c & 15);
      float v = (k < 256) ? W[(size_t)k*1024 + gc] : U[(size_t)(k-256)*1024 + gc];
      U_T[c][swz8(c, k >> 3) | (k & 7)] = (bf16)v;
    }
  }

  int gb = tid >> 4, gu = tid & 15;        // gate thread: batch gb, unit j0+gu (coalesced h store)
  float c_state = 0.f, h_state = 0.f;
  float bi = 0.f, bff = 0.f, bgg = 0.f, boo = 0.f;
  if (stage == 1) {
    const float* bias = dir ? bb1 : fb1;
    bi  = bias[0*256 + j0 + gu];
    bff = bias[1*256 + j0 + gu];
    bgg = bias[2*256 + j0 + gu];
    boo = bias[3*256 + j0 + gu];
  }
  int wave = tid >> 6, lane = tid & 63, l15 = lane & 15, quad = lane >> 4;
  int m0 = (wave & 1)*16, n0 = (wave >> 1)*16;

  // per-granule LDS element offsets (constant over t). granule j covers 2 units (u64 = 2 u32).
  int laddr[16];
  #pragma unroll
  for (int j = 0; j < 16; ++j) {
    int g = (j & 7)*512 + tid;              // granule index within a slot (0..4095)
    int kb = g >> 8, rem = g & 255;
    int row = rem >> 3, up = (rem & 7)*2;
    int p = (j >> 3)*256 + kb*16 + up;      // hA k-position (h1-half at +256 for j>=8)
    laddr[j] = row*512 + swz8(row, p >> 3) + (p & 7);
  }
  bf16* hAf = &hA[0][0];
  __syncthreads();

  for (int t = 0; t < 127; ++t) {
    // step-constant operands (independent of handoff — issue early)
    float p_i = bi, p_f = bff, p_g = bgg, p_o = boo;
    if (stage == 0) {
      const float* p = pre + ((size_t)t*32 + gb)*1024 + j0 + gu;
      p_i = p[0]; p_f = p[256]; p_g = p[512]; p_o = p[768];
    }
    unsigned char msk = mgl[t*32 + gb];

    uint64_t v[16];
    if (stage == 0) {
      const uint64_t* s0 = (const uint64_t*)h0 + (size_t)t*4096;      // h0(t-1) @ slot t
      if (t > 0) {
        #pragma unroll
        for (int j = 0; j < 8; ++j) v[j] = sys_load_u64(s0 + (j*512 + tid));  // all in flight
        uint64_t pat = ((uint64_t)t << 48) | ((uint64_t)t << 16);
        #pragma unroll
        for (int j = 0; j < 8; ++j) {
          int sp = 0;
          while ((v[j] & 0xFFFF0000FFFF0000ull) != pat) {
            if (++sp > 1024) __builtin_amdgcn_s_sleep(2);
            if (sp > (1<<22)) break;   // hang safety
            v[j] = sys_load_u64(s0 + (j*512 + tid));
          }
        }
      } else {
        #pragma unroll
        for (int j = 0; j < 8; ++j) v[j] = 0;
      }
      #pragma unroll
      for (int j = 0; j < 8; ++j) {
        uint32_t pk = (uint32_t)(v[j] & 0xFFFF) | ((uint32_t)((v[j] >> 32) & 0xFFFF) << 16);
        *(uint32_t*)&hAf[laddr[j]] = pk;
      }
    } else {
      const uint64_t* s0 = (const uint64_t*)h0 + (size_t)(t+1)*4096;  // h0(t)   @ slot t+1
      const uint64_t* s1 = (const uint64_t*)h1 + (size_t)t*4096;      // h1(t-1) @ slot t
      #pragma unroll
      for (int j = 0; j < 8; ++j) v[j] = sys_load_u64(s0 + (j*512 + tid));
      if (t > 0) {
        #pragma unroll
        for (int j = 8; j < 16; ++j) v[j] = sys_load_u64(s1 + ((j-8)*512 + tid));
      } else {
        #pragma unroll
        for (int j = 8; j < 16; ++j) v[j] = 0;
      }
      uint64_t pat0 = ((uint64_t)(t+1) << 48) | ((uint64_t)(t+1) << 16);
      #pragma unroll
      for (int j = 0; j < 8; ++j) {
        int sp = 0;
        while ((v[j] & 0xFFFF0000FFFF0000ull) != pat0) {
          if (++sp > 1024) __builtin_amdgcn_s_sleep(2);
          if (sp > (1<<22)) break;
          v[j] = sys_load_u64(s0 + (j*512 + tid));
        }
      }
      if (t > 0) {
        uint64_t pat1 = ((uint64_t)t << 48) | ((uint64_t)t << 16);
        #pragma unroll
        for (int j = 8; j < 16; ++j) {
          int sp = 0;
          while ((v[j] & 0xFFFF0000FFFF0000ull) != pat1) {
            if (++sp > 1024) __builtin_amdgcn_s_sleep(2);
            if (sp > (1<<22)) break;
            v[j] = sys_load_u64(s1 + ((j-8)*512 + tid));
          }
        }
      }
      #pragma unroll
      for (int j = 0; j < 16; ++j) {
        uint32_t pk = (uint32_t)(v[j] & 0xFFFF) | ((uint32_t)((v[j] >> 32) & 0xFFFF) << 16);
        *(uint32_t*)&hAf[laddr[j]] = pk;
      }
    }
    __syncthreads();   // [B1] hA complete

    // MFMA: z[32b][64c] = hA[32][K] * U_T[64c][K]^T ; two acc chains to halve MFMA latency
    f32x4 zac;
    {
      f32x4 a0 = {0.f,0.f,0.f,0.f}, a1 = {0.f,0.f,0.f,0.f};
      if (stage == 0) {
        #pragma unroll
        for (int kc = 0; kc < 128; kc += 32) {
          int kb = (kc >> 3) + quad;
          a0 = __builtin_amdgcn_mfma_f32_16x16x32_bf16(
                 *(const bf16x8*)&hA[m0 + l15][swz8(m0 + l15, kb)],
                 *(const bf16x8*)&U_T[n0 + l15][swz8(n0 + l15, kb)], a0, 0, 0, 0);
        }
        #pragma unroll
        for (int kc = 128; kc < 256; kc += 32) {
          int kb = (kc >> 3) + quad;
          a1 = __builtin_amdgcn_mfma_f32_16x16x32_bf16(
                 *(const bf16x8*)&hA[m0 + l15][swz8(m0 + l15, kb)],
                 *(const bf16x8*)&U_T[n0 + l15][swz8(n0 + l15, kb)], a1, 0, 0, 0);
        }
      } else {
        #pragma unroll
        for (int kc = 0; kc < 256; kc += 32) {
          int kb = (kc >> 3) + quad;
          a0 = __builtin_amdgcn_mfma_f32_16x16x32_bf16(
                 *(const bf16x8*)&hA[m0 + l15][swz8(m0 + l15, kb)],
                 *(const bf16x8*)&U_T[n0 + l15][swz8(n0 + l15, kb)], a0, 0, 0, 0);
        }
        #pragma unroll
        for (int kc = 256; kc < 512; kc += 32) {
          int kb = (kc >> 3) + quad;
          a1 = __builtin_amdgcn_mfma_f32_16x16x32_bf16(
                 *(const bf16x8*)&hA[m0 + l15][swz8(m0 + l15, kb)],
                 *(const bf16x8*)&U_T[n0 + l15][swz8(n0 + l15, kb)], a1, 0, 0, 0);
        }
      }
      zac = a0 + a1;
    }
    #pragma unroll
    for (int r = 0; r < 4; ++r) z_s[m0 + quad*4 + r][n0 + l15] = zac[r];
    __syncthreads();   // [B2] z ready; also fences hA reads vs next-step writes

    // gates (fp32, Keras i,f,g,o); lds col for (gate g, unit gu) = g*16+gu
    float zi = z_s[gb][ 0 + gu] + p_i;
    float zf = z_s[gb][16 + gu] + p_f;
    float zg = z_s[gb][32 + gu] + p_g;
    float zo = z_s[gb][48 + gu] + p_o;
    float ig = 1.f/(1.f + expf(-zi));
    float fg = 1.f/(1.f + expf(-zf));
    float gg = tanhf(zg);
    float og = 1.f/(1.f + expf(-zo));
    float cn = fg*c_state + ig*gg;
    float hn = og*tanhf(cn);
    if (msk) { c_state = cn; h_state = hn; }

    // fire-and-forget tagged store: {tag=t+1, h}; coalesced (index = blk*512 + tid)
    bf16 hv = (bf16)h_state;
    unsigned short hb;
    __builtin_memcpy(&hb, &hv, 2);
    uint32_t val = ((uint32_t)(t+1) << 16) | (uint32_t)hb;
    sys_store_u32(hout + (size_t)(t+1)*8192 + blk*512 + tid, val);
  }
}

// ---------------- ctx assembly from tagged h1 (extract lo16) ----------------
// ctx[b*126+tau][0:256]=h1f(tau)@slot tau+1, [256:512]=h1b(tau+1)@slot tau+2
__global__ __launch_bounds__(256) void ctx_kernel(
    const uint32_t* __restrict__ h1f, const uint32_t* __restrict__ h1b, bf16* __restrict__ ctx)
{
  int tau = blockIdx.x;   // 0..125
  int b = blockIdx.y;     // 0..31
  int k = threadIdx.x;    // 0..255
  size_t r = (size_t)(b*126 + tau)*512;
  uint32_t vf = h1f[(size_t)(tau+1)*8192 + (k>>4)*512 + b*16 + (k&15)];
  uint32_t vb = h1b[(size_t)(tau+2)*8192 + (k>>4)*512 + b*16 + (k&15)];
  ((unsigned short*)ctx)[r + k]       = (unsigned short)(vf & 0xFFFF);
  ((unsigned short*)ctx)[r + 256 + k] = (unsigned short)(vb & 0xFFFF);
}

// ---------------- NSP head ----------------
__global__ __launch_bounds__(256) void nsp_kernel(
    const bf16* __restrict__ ctx, const float* __restrict__ Wn,
    const float* __restrict__ bn, float* __restrict__ out)
{
  int b = blockIdx.x, tid = threadIdx.x;
  const unsigned short* cb = (const unsigned short*)ctx;
  float a0 = 0.f, a1 = 0.f;
  for (int flat = tid; flat < 64512; flat += 256) {
    int tau = flat >> 9, k = flat & 511;
    float cv = __uint_as_float((unsigned)cb[(size_t)(b*126 + tau)*512 + k] << 16);
    float2 w = *(const float2*)(Wn + 2*(size_t)flat);
    a0 += cv*w.x; a1 += cv*w.y;
  }
  __shared__ float r0[256], r1[256];
  r0[tid] = a0; r1[tid] = a1;
  __syncthreads();
  for (int s = 128; s > 0; s >>= 1) {
    if (tid < s) { r0[tid] += r0[tid+s]; r1[tid] += r1[tid+s]; }
    __syncthreads();
  }
  if (tid == 0) { out[b*2+0] = r0[0] + bn[0]; out[b*2+1] = r1[0] + bn[1]; }
}

// ---------------- launch ----------------
extern "C" void kernel_launch(void* const* d_in, const int* in_sizes, int n_in,
                              void* d_out, int out_size, void* d_ws, size_t ws_size,
                              hipStream_t stream)
{
  const int*   x   = (const int*)d_in[0];
  const float* tab = (const float*)d_in[1];
  const float* fW  = (const float*)d_in[2];
  const float* fU  = (const float*)d_in[3];
  const float* fb  = (const float*)d_in[4];
  const float* bW  = (const float*)d_in[5];
  const float* bU  = (const float*)d_in[6];
  const float* bb  = (const float*)d_in[7];
  const float* Wp  = (const float*)d_in[8];
  const float* bp  = (const float*)d_in[9];
  const float* Wn  = (const float*)d_in[10];
  const float* bn  = (const float*)d_in[11];
  float* out = (float*)d_out;
  char* ws = (char*)d_ws;

  unsigned char* mf = (unsigned char*)(ws + OFF_MF);
  unsigned char* mb = (unsigned char*)(ws + OFF_MB);
  uint32_t* h0f = (uint32_t*)(ws + OFF_H0F);
  uint32_t* h0b = (uint32_t*)(ws + OFF_H0B);
  uint32_t* h1f = (uint32_t*)(ws + OFF_H1F);
  uint32_t* h1b = (uint32_t*)(ws + OFF_H1B);
  bf16* xf    = (bf16*)(ws + OFF_XF);
  bf16* xb    = (bf16*)(ws + OFF_XB);
  bf16* fW0T  = (bf16*)(ws + OFF_FW0T);
  bf16* bW0T  = (bf16*)(ws + OFF_BW0T);
  float* pre0f = (float*)(ws + OFF_PRE0F);
  float* pre0b = (float*)(ws + OFF_PRE0B);
  bf16* WpT   = (bf16*)(ws + OFF_WPT);   // aliases pre0f/pre0b (dead after recur)
  bf16* ctx   = (bf16*)(ws + OFF_CTX);   // aliases xf/xb (dead after pre-GEMMs)

  // zero tags in all four tagged h arrays (tag 0 = invalid; slot 0 never written)
  hipMemsetAsync(ws + OFF_H0F, 0, 4*(size_t)TAG_ONE, stream);

  embed_kernel<<<dim3(127, 32), 256, 0, stream>>>(x, tab, xf, xb, mf, mb);

  transpose_to_bf16<<<dim3(16, 4),  256, 0, stream>>>(fW, fW0T, 256, 1024);
  transpose_to_bf16<<<dim3(16, 4),  256, 0, stream>>>(bW, bW0T, 256, 1024);

  gemm_bf16<<<dim3(32, 8), 256, 0, stream>>>(xf, fW0T, fb, pre0f, 4064, 1024, 256);
  gemm_bf16<<<dim3(32, 8), 256, 0, stream>>>(xb, bW0T, bb, pre0b, 4064, 1024, 256);

  recur_kernel<<<64, 512, 0, stream>>>(
      pre0f, pre0b,
      fU, bU,
      fW + 262144, fU + 262144, bW + 262144, bU + 262144,
      fb + 1024, bb + 1024,
      mf, mb, h0f, h0b, h1f, h1b);

  // Wp transpose AFTER recur: WPT aliases the pre buffers
  transpose_to_bf16<<<dim3(500, 8), 256, 0, stream>>>(Wp, WpT, 512, 32000);

  ctx_kernel<<<dim3(126, 32), 256, 0, stream>>>(h1f, h1b, ctx);

  gemm_bf16<<<dim3(32, 250), 256, 0, stream>>>(ctx, WpT, bp, out, 4032, 32000, 512);

  nsp_kernel<<<32, 256, 0, stream>>>(ctx, Wn, bn, out + (size_t)4032*32000);
}